// Round 5
// baseline (358.676 us; speedup 1.0000x reference)
//
#include <hip/hip_runtime.h>

typedef _Float16 f16;
typedef _Float16 f16x8 __attribute__((ext_vector_type(8)));
typedef _Float16 f16x4 __attribute__((ext_vector_type(4)));
typedef float    f32x4 __attribute__((ext_vector_type(4)));
typedef float    f32x16 __attribute__((ext_vector_type(16)));
typedef unsigned int u32t;

#define AS1 __attribute__((address_space(1)))
#define AS3 __attribute__((address_space(3)))

static __device__ __forceinline__ void gload_lds16(const void* g, void* l) {
  __builtin_amdgcn_global_load_lds((const AS1 u32t*)g, (AS3 u32t*)l, 16, 0, 0);
}

static __device__ __forceinline__ f16x8 zero8() {
  f16x8 z;
#pragma unroll
  for (int j = 0; j < 8; ++j) z[j] = (f16)0;
  return z;
}

// ---------------- convert x (fp32 -> fp16) ----------------
__global__ void k_cvt_x(const float* __restrict__ in, f16* __restrict__ out, int n4) {
  int stride = gridDim.x * blockDim.x;
  for (int i = blockIdx.x * blockDim.x + threadIdx.x; i < n4; i += stride) {
    float4 v = ((const float4*)in)[i];
    f16x4 o;
    o[0] = (f16)v.x; o[1] = (f16)v.y; o[2] = (f16)v.z; o[3] = (f16)v.w;
    ((f16x4*)out)[i] = o;
  }
}

// ---------------- convert + transpose W: [1280][N] f32 -> [N][1280] f16 ----------------
__global__ void k_cvt_w_t(const float* __restrict__ W, f16* __restrict__ Wt, int N) {
  __shared__ float T[32][33];
  int bk = blockIdx.x % 40;          // 1280/32
  int bn = blockIdx.x / 40;
  int k0 = bk * 32, n0 = bn * 32;
  int r = threadIdx.x >> 5;          // 0..7
  int c = threadIdx.x & 31;
#pragma unroll
  for (int i = 0; i < 4; ++i)
    T[r + i * 8][c] = W[(size_t)(k0 + r + i * 8) * N + n0 + c];
  __syncthreads();
#pragma unroll
  for (int i = 0; i < 4; ++i)
    Wt[(size_t)(n0 + r + i * 8) * 1280 + k0 + c] = (f16)T[c][r + i * 8];
}

// ========== 128x128 GEMM (R0 structure), 32x32x16 MFMA, LDS-bounce epilogue ==========
// C[M=8192, NCOLS] = A[8192,1280] * Bt[NCOLS,1280]^T + bias
// 256 thr = 4 waves (2M x 2N); per-wave 64x64 = 2x2 frags of 32x32; BK=64, 20 tiles.
// LDS 32KB: sA 16KB + sB 16KB, single-buffered (2 barriers/tile) -> 2-3 blocks/CU,
// cross-block overlap hides drain stalls (m114; R0 measured 951 TF with this shape).
// Swizzle (R0/R2-proven, 0 conflicts): tile rows 128B; phys 16B-chunk = chunk^(row&7);
// staging = linear LDS dest + pre-swizzled global source column.
// Epilogue: acc -> 32KB swizzled LDS chunk (per mf half) -> row-major readback ->
// dwordx4 (f32) / f16x4 stores. 16 vector stores/thread instead of 64 scalar.

template<int NCOLS, bool F16OUT>
__global__ __launch_bounds__(256, 2)
void gemm_nt(const f16* __restrict__ A, const f16* __restrict__ Bt,
             const float* __restrict__ bias, void* __restrict__ Cout)
{
  __shared__ __align__(16) char lds[32768];
  char* const sA = lds;
  char* const sB = lds + 16384;

  const int tid = threadIdx.x;
  const int wave = tid >> 6, lane = tid & 63;
  const int x7 = lane & 7, l5 = lane >> 5, r31 = lane & 31;
  const int wm = wave >> 1, wn = wave & 1;

  constexpr int NBN = NCOLS / 128;
  constexpr int NWG = 64 * NBN;
  const int bid = blockIdx.x;
  const int wgid = (bid & 7) * (NWG / 8) + (bid >> 3);   // XCD swizzle (NWG%8==0)
  const int bm = wgid / NBN, bn = wgid % NBN;
  const long row0 = (long)bm * 128, col0 = (long)bn * 128;

  // staging geometry (R0): per wave 4 segments of 1KB per matrix per tile.
  int segr[4], segoff[4];
#pragma unroll
  for (int i = 0; i < 4; ++i) {
    int o = (wave * 4 + i) * 1024 + lane * 16;
    int r = o >> 7, cb = o & 127;
    segr[i] = r;
    segoff[i] = cb ^ ((r & 7) << 4);
  }
  const char* Ab = (const char*)A;
  const char* Bb = (const char*)Bt;

  // fragment read offsets: frag (mf|nf), kstep ks: row = base + r31,
  // byte = row*128 + ((ks*2 + l5) ^ x7)*16   (row&7 == x7)
  int offA[2], offB[2], kchunk[4];
#pragma unroll
  for (int f = 0; f < 2; ++f) {
    offA[f] = (wm * 64 + f * 32 + r31) << 7;
    offB[f] = (wn * 64 + f * 32 + r31) << 7;
  }
#pragma unroll
  for (int ks = 0; ks < 4; ++ks) kchunk[ks] = ((ks * 2 + l5) ^ x7) << 4;

  f32x16 acc[2][2];
#pragma unroll
  for (int i = 0; i < 2; ++i)
#pragma unroll
    for (int j = 0; j < 2; ++j)
#pragma unroll
      for (int r = 0; r < 16; ++r) acc[i][j][r] = 0.f;

  for (int kt = 0; kt < 20; ++kt) {
    __syncthreads();   // previous compute done before overwrite
#pragma unroll
    for (int i = 0; i < 4; ++i) {
      const char* ga = Ab + ((row0 + segr[i]) * 1280 + kt * 64) * 2 + segoff[i];
      gload_lds16(ga, sA + (wave * 4 + i) * 1024);
      const char* gb = Bb + ((col0 + segr[i]) * 1280 + kt * 64) * 2 + segoff[i];
      gload_lds16(gb, sB + (wave * 4 + i) * 1024);
    }
    __syncthreads();   // drains vmcnt: tile ready

    f16x8 af[2][4], bf[2][4];
#pragma unroll
    for (int f = 0; f < 2; ++f)
#pragma unroll
      for (int ks = 0; ks < 4; ++ks) {
        af[f][ks] = *(const f16x8*)(sA + offA[f] + kchunk[ks]);
        bf[f][ks] = *(const f16x8*)(sB + offB[f] + kchunk[ks]);
      }
    __builtin_amdgcn_s_setprio(1);
#pragma unroll
    for (int ks = 0; ks < 4; ++ks)
#pragma unroll
      for (int mf = 0; mf < 2; ++mf)
#pragma unroll
        for (int nf = 0; nf < 2; ++nf)
          acc[mf][nf] = __builtin_amdgcn_mfma_f32_32x32x16_f16(
              af[mf][ks], bf[nf][ks], acc[mf][nf], 0, 0, 0);
    __builtin_amdgcn_s_setprio(0);
  }

  // ---- epilogue: LDS bounce, vectorized stores ----
  // C frag layout (32x32): col = lane&31, row = (reg&3) + 8*(reg>>2) + 4*(lane>>5)
  float* bb = (float*)lds;
  const int cc0 = wn * 64 + r31;
  const float bv0 = bias[col0 + cc0];
  const float bv1 = bias[col0 + cc0 + 32];
  const int lrow_rd = tid >> 2, qc = tid & 3;
  const long grow_base = row0 + (lrow_rd >> 5) * 64 + (lrow_rd & 31);

#pragma unroll
  for (int mf = 0; mf < 2; ++mf) {
    __syncthreads();   // tile reads (mf=0) / prev readback (mf=1) done
#pragma unroll
    for (int nf = 0; nf < 2; ++nf) {
      const int cc = cc0 + nf * 32;
      const float bv = nf ? bv1 : bv0;
#pragma unroll
      for (int r = 0; r < 16; ++r) {
        int lrow = wm * 32 + (r & 3) + 8 * (r >> 2) + 4 * l5;
        bb[lrow * 128 + (((cc >> 2) ^ (lrow & 7)) << 2) + (cc & 3)] = acc[mf][nf][r] + bv;
      }
    }
    __syncthreads();
    const long grow = grow_base + mf * 32;
#pragma unroll
    for (int i = 0; i < 8; ++i) {
      int ch = qc * 8 + i;
      f32x4 v = *(const f32x4*)(bb + lrow_rd * 128 + ((ch ^ (lrow_rd & 7)) << 2));
      long c = col0 + ch * 4;
      if (F16OUT) {
        f16x4 h; h[0] = (f16)v[0]; h[1] = (f16)v[1]; h[2] = (f16)v[2]; h[3] = (f16)v[3];
        *(f16x4*)((f16*)Cout + grow * NCOLS + c) = h;
      } else {
        *(f32x4*)((float*)Cout + grow * NCOLS + c) = v;
      }
    }
  }
}

// ---------------- V transpose: qkv v-part -> vt[b*16+h][80][2048] ----------------
__global__ void k_vt(const f16* __restrict__ qkv, f16* __restrict__ vt) {
  __shared__ __align__(16) f16 T[128 * 136];
  int bid = blockIdx.x;              // 64 bh * 16 s-chunks
  int sc16 = bid & 15, bh = bid >> 4;
  int b = bh >> 4, h = bh & 15;
  int s0 = sc16 * 128;
  int t = threadIdx.x;
#pragma unroll
  for (int i = 0; i < 5; ++i) {
    int cid = i * 256 + t;           // 1280 = 128 s * 10 chunks
    int s = cid / 10, c = cid % 10;
    const f16* g = qkv + (size_t)((s0 + s) * 4 + b) * 3840 + 2560 + h * 80 + c * 8;
    f16x8 v = *(const f16x8*)g;
    int phys = c ^ ((s >> 3) & 7);
    *(f16x8*)(T + s * 136 + phys * 8) = v;
  }
  __syncthreads();
#pragma unroll
  for (int i = 0; i < 5; ++i) {
    int oid = i * 256 + t;           // 1280 = 80 hd * 16 s-subchunks
    int sc8 = oid & 15, hd = oid >> 4;
    f16x8 o;
#pragma unroll
    for (int j = 0; j < 8; ++j) {
      int row = sc8 * 8 + j;
      int phys = (hd >> 3) ^ (sc8 & 7);
      o[j] = T[row * 136 + phys * 8 + (hd & 7)];
    }
    *(f16x8*)(vt + (size_t)(bh * 80 + hd) * 2048 + s0 + sc8 * 8) = o;
  }
}

// ---------------- windowed attention ----------------
// block: (b, h, seg, qc) ; 512 threads = 8 waves * 16 queries
__global__ __launch_bounds__(512, 2)
void k_attn(const f16* __restrict__ qkv, const f16* __restrict__ vt,
            f16* __restrict__ ctx)
{
  __shared__ __align__(16) f16 sK[256 * 104];   // keys x (80 + zero-pad to 96, stride 104)
  __shared__ __align__(16) f16 sV[80 * 264];    // hd x 256 keys (stride 264)
  __shared__ __align__(16) f16 sP[128 * 72];    // q x 64-key chunk (stride 72)

  const int bid = blockIdx.x;                   // 1024
  const int qc = bid & 1, seg = (bid >> 1) & 7, h = (bid >> 4) & 15, b = bid >> 8;
  const int t = threadIdx.x;
  const int wave = t >> 6, lane = t & 63;
  const int s_key0 = seg * 256;

  // stage K (k-part of qkv, col base 1280 + h*80)
#pragma unroll
  for (int i = 0; i < 5; ++i) {
    int cid = i * 512 + t;                      // 2560 = 256 keys * 10 chunks
    int key = cid / 10, c = cid % 10;
    const f16* g = qkv + (size_t)((s_key0 + key) * 4 + b) * 3840 + 1280 + h * 80 + c * 8;
    *(f16x8*)(sK + key * 104 + c * 8) = *(const f16x8*)g;
  }
  { // zero cols 80..95
    int key = t >> 1, c = t & 1;
    *(f16x8*)(sK + key * 104 + 80 + c * 8) = zero8();
  }
  // stage V from vt
#pragma unroll
  for (int i = 0; i < 5; ++i) {
    int cid = i * 512 + t;                      // 2560 = 80 hd * 32 chunks
    int hd = cid >> 5, c = cid & 31;
    const f16* g = vt + (size_t)((b * 16 + h) * 80 + hd) * 2048 + s_key0 + c * 8;
    *(f16x8*)(sV + hd * 264 + c * 8) = *(const f16x8*)g;
  }

  // Q fragments direct from global (col base h*80); wave owns 16 queries
  const int q0 = s_key0 + qc * 128 + wave * 16;
  const int rl = lane & 15, g = lane >> 4;
  f16x8 qf[3];
  {
    const f16* gq = qkv + (size_t)((q0 + rl) * 4 + b) * 3840 + h * 80;
    qf[0] = *(const f16x8*)(gq + g * 8);
    qf[1] = *(const f16x8*)(gq + 32 + g * 8);
    if (g < 2) qf[2] = *(const f16x8*)(gq + 64 + g * 8);
    else       qf[2] = zero8();
  }
  __syncthreads();

  // QK^T : sc[nt] covers keys nt*16+(lane&15), rows g*4+r
  f32x4 sc[16];
#pragma unroll
  for (int nt = 0; nt < 16; ++nt) sc[nt] = (f32x4){0.f, 0.f, 0.f, 0.f};
#pragma unroll
  for (int nt = 0; nt < 16; ++nt) {
#pragma unroll
    for (int kk = 0; kk < 3; ++kk) {
      f16x8 bf = *(const f16x8*)(sK + (nt * 16 + rl) * 104 + kk * 32 + g * 8);
      sc[nt] = __builtin_amdgcn_mfma_f32_16x16x32_f16(qf[kk], bf, sc[nt], 0, 0, 0);
    }
  }

  // softmax (exact, full 256-key window in regs)
  const float scale = 0.11180339887498949f;
  float inv[4];
#pragma unroll
  for (int r = 0; r < 4; ++r) {
    float m = -1e30f;
#pragma unroll
    for (int nt = 0; nt < 16; ++nt) m = fmaxf(m, sc[nt][r]);
#pragma unroll
    for (int off = 8; off >= 1; off >>= 1) m = fmaxf(m, __shfl_xor(m, off));
    m *= scale;
    float sum = 0.f;
#pragma unroll
    for (int nt = 0; nt < 16; ++nt) {
      float p = __expf(sc[nt][r] * scale - m);
      sc[nt][r] = p;
      sum += p;
    }
#pragma unroll
    for (int off = 8; off >= 1; off >>= 1) sum += __shfl_xor(sum, off);
    inv[r] = 1.0f / sum;
  }

  // PV in 4 chunks of 64 keys; P bounced through WAVE-PRIVATE sP rows.
  // No block barriers: each wave reads only rows it wrote (compiler orders
  // same-wave LDS write->read via lgkmcnt).
  f32x4 o[5];
#pragma unroll
  for (int nt = 0; nt < 5; ++nt) o[nt] = (f32x4){0.f, 0.f, 0.f, 0.f};
  const int prow0 = wave * 16;
  for (int ch = 0; ch < 4; ++ch) {
#pragma unroll
    for (int f = 0; f < 4; ++f) {
      int nt = ch * 4 + f;
#pragma unroll
      for (int r = 0; r < 4; ++r)
        sP[(prow0 + g * 4 + r) * 72 + f * 16 + rl] = (f16)sc[nt][r];
    }
#pragma unroll
    for (int kk = 0; kk < 2; ++kk) {
      f16x8 pa = *(const f16x8*)(sP + (prow0 + rl) * 72 + kk * 32 + g * 8);
#pragma unroll
      for (int nt = 0; nt < 5; ++nt) {
        f16x8 vb = *(const f16x8*)(sV + (nt * 16 + rl) * 264 + ch * 64 + kk * 32 + g * 8);
        o[nt] = __builtin_amdgcn_mfma_f32_16x16x32_f16(pa, vb, o[nt], 0, 0, 0);
      }
    }
  }

  // epilogue: normalize, store ctx fp16
#pragma unroll
  for (int nt = 0; nt < 5; ++nt) {
    int hd = nt * 16 + rl;
#pragma unroll
    for (int r = 0; r < 4; ++r) {
      long qrow = q0 + g * 4 + r;
      float v = o[nt][r] * inv[r];
      ctx[(qrow * 4 + b) * 1280 + h * 80 + hd] = (f16)v;
    }
  }
}

extern "C" void kernel_launch(void* const* d_in, const int* in_sizes, int n_in,
                              void* d_out, int out_size, void* d_ws, size_t ws_size,
                              hipStream_t stream)
{
  const float* x     = (const float*)d_in[0];
  const float* Wqkv  = (const float*)d_in[1];
  const float* bqkv  = (const float*)d_in[2];
  const float* Wproj = (const float*)d_in[3];
  const float* bproj = (const float*)d_in[4];

  char* ws = (char*)d_ws;
  f16* X16   = (f16*)(ws);                 // 20,971,520 B (reused as CTX16 after gemm1)
  f16* WQT   = (f16*)(ws + 20971520);      //  9,830,400 B
  f16* WPT   = (f16*)(ws + 30801920);      // 13,107,200 B
  f16* QKV16 = (f16*)(ws + 43909120);      // 62,914,560 B
  f16* VT    = (f16*)(ws + 106823680);     // 20,971,520 B  (total 127,795,200 B)
  f16* CTX16 = X16;                        // x dead after gemm1

  k_cvt_x<<<4096, 256, 0, stream>>>(x, X16, 8192 * 1280 / 4);
  k_cvt_w_t<<<40 * 120, 256, 0, stream>>>(Wqkv, WQT, 3840);
  k_cvt_w_t<<<40 * 160, 256, 0, stream>>>(Wproj, WPT, 5120);
  gemm_nt<3840, true ><<<64 * 30, 256, 0, stream>>>(X16, WQT, bqkv, QKV16);
  k_vt<<<1024, 256, 0, stream>>>(QKV16, VT);
  k_attn<<<1024, 512, 0, stream>>>(QKV16, VT, CTX16);
  gemm_nt<5120, false><<<64 * 40, 256, 0, stream>>>(CTX16, WPT, bproj, d_out);
}

// Round 6
// 290.647 us; speedup vs baseline: 1.2341x; 1.2341x over previous
//
#include <hip/hip_runtime.h>

typedef _Float16 f16;
typedef _Float16 f16x8 __attribute__((ext_vector_type(8)));
typedef _Float16 f16x4 __attribute__((ext_vector_type(4)));
typedef float    f32x4 __attribute__((ext_vector_type(4)));
typedef unsigned int u32t;

#define AS1 __attribute__((address_space(1)))
#define AS3 __attribute__((address_space(3)))

static __device__ __forceinline__ void gload_lds16(const void* g, void* l) {
  __builtin_amdgcn_global_load_lds((const AS1 u32t*)g, (AS3 u32t*)l, 16, 0, 0);
}

static __device__ __forceinline__ f16x8 zero8() {
  f16x8 z;
#pragma unroll
  for (int j = 0; j < 8; ++j) z[j] = (f16)0;
  return z;
}

// ---------------- convert x (fp32 -> fp16) ----------------
__global__ void k_cvt_x(const float* __restrict__ in, f16* __restrict__ out, int n4) {
  int stride = gridDim.x * blockDim.x;
  for (int i = blockIdx.x * blockDim.x + threadIdx.x; i < n4; i += stride) {
    float4 v = ((const float4*)in)[i];
    f16x4 o;
    o[0] = (f16)v.x; o[1] = (f16)v.y; o[2] = (f16)v.z; o[3] = (f16)v.w;
    ((f16x4*)out)[i] = o;
  }
}

// ---------------- convert + transpose W: [1280][N] f32 -> [N][1280] f16 ----------------
__global__ void k_cvt_w_t(const float* __restrict__ W, f16* __restrict__ Wt, int N) {
  __shared__ float T[32][33];
  int bk = blockIdx.x % 40;          // 1280/32
  int bn = blockIdx.x / 40;
  int k0 = bk * 32, n0 = bn * 32;
  int r = threadIdx.x >> 5;          // 0..7
  int c = threadIdx.x & 31;
#pragma unroll
  for (int i = 0; i < 4; ++i)
    T[r + i * 8][c] = W[(size_t)(k0 + r + i * 8) * N + n0 + c];
  __syncthreads();
#pragma unroll
  for (int i = 0; i < 4; ++i)
    Wt[(size_t)(n0 + r + i * 8) * 1280 + k0 + c] = (f16)T[c][r + i * 8];
}

// ---------------- NT GEMM (exact R0 structure, 951 TF measured) ----------------
// C[M,NCOLS] = A[M,1280] * Bt[NCOLS,1280]^T + bias
// 256 thr = 4 waves (2x2); 128x128 tile, BK=64, single-buffered, 2 barriers/tile.
// Swizzle: phys 16B-chunk = chunk ^ (row&7), 128B rows (measured: 0 conflicts).
// F16OUT epilogue: LDS bounce (tile LDS is dead) -> 8 coalesced f16x8 stores/thread
// instead of 64 scalar 2B stores (R0 gemm1 was ~615 TF vs gemm2 951 TF: scalar
// f16 scatter-writes were the gap).
template<int NCOLS, bool F16OUT>
__global__ __launch_bounds__(256, 2)
void gemm_nt(const f16* __restrict__ A, const f16* __restrict__ Bt,
             const float* __restrict__ bias, void* __restrict__ Cout)
{
  __shared__ __align__(16) char lds[32768];
  f16* const sA = (f16*)lds;
  f16* const sB = (f16*)(lds + 16384);
  const int tid = threadIdx.x;
  const int wave = tid >> 6, lane = tid & 63;
  constexpr int NBN = NCOLS / 128;
  const int bm = blockIdx.x / NBN, bn = blockIdx.x % NBN;
  const long row0 = (long)bm * 128, col0 = (long)bn * 128;

  f32x4 acc[4][4];
#pragma unroll
  for (int i = 0; i < 4; ++i)
#pragma unroll
    for (int j = 0; j < 4; ++j) acc[i][j] = (f32x4){0.f, 0.f, 0.f, 0.f};

  const int wr = (wave >> 1) * 64, wc = (wave & 1) * 64;

  // staging geometry: per wave 4 segments of 1KB per matrix per tile.
  int segr[4], segoff[4];
#pragma unroll
  for (int i = 0; i < 4; ++i) {
    int o = (wave * 4 + i) * 1024 + lane * 16;
    int r = o >> 7, cb = o & 127;
    segr[i] = r;
    segoff[i] = cb ^ ((r & 7) << 4);
  }

  const char* Ab = (const char*)A;
  const char* Bb = (const char*)Bt;

  for (int kt = 0; kt < 20; ++kt) {
    __syncthreads();   // previous compute done before overwrite
#pragma unroll
    for (int i = 0; i < 4; ++i) {
      const char* ga = Ab + ((row0 + segr[i]) * 1280 + kt * 64) * 2 + segoff[i];
      gload_lds16(ga, (char*)sA + (wave * 4 + i) * 1024);
      const char* gb = Bb + ((col0 + segr[i]) * 1280 + kt * 64) * 2 + segoff[i];
      gload_lds16(gb, (char*)sB + (wave * 4 + i) * 1024);
    }
    __syncthreads();   // compiler drains vmcnt before barrier

#pragma unroll
    for (int kk = 0; kk < 2; ++kk) {
      const int rl = lane & 15, g = lane >> 4, x7 = lane & 7;
      const int ph = (kk * 4 + g) ^ x7;
      f16x8 af[4], bf[4];
#pragma unroll
      for (int mt = 0; mt < 4; ++mt)
        af[mt] = *(const f16x8*)(sA + (wr + mt * 16 + rl) * 64 + ph * 8);
#pragma unroll
      for (int nt = 0; nt < 4; ++nt)
        bf[nt] = *(const f16x8*)(sB + (wc + nt * 16 + rl) * 64 + ph * 8);
#pragma unroll
      for (int mt = 0; mt < 4; ++mt)
#pragma unroll
        for (int nt = 0; nt < 4; ++nt)
          acc[mt][nt] = __builtin_amdgcn_mfma_f32_16x16x32_f16(af[mt], bf[nt], acc[mt][nt], 0, 0, 0);
    }
  }

  const int rl = lane & 15, g = lane >> 4;
  if (F16OUT) {
    // ---- LDS-bounce epilogue: cb[128 rows][128 f16], chunk^(row&7) swizzle ----
    __syncthreads();                      // all tile reads done; LDS reusable
    f16* cb = (f16*)lds;
#pragma unroll
    for (int mt = 0; mt < 4; ++mt) {
#pragma unroll
      for (int nt = 0; nt < 4; ++nt) {
        int colc = wc + nt * 16 + rl;
        float bv = bias[col0 + colc];
#pragma unroll
        for (int r = 0; r < 4; ++r) {
          int lrow = wr + mt * 16 + g * 4 + r;
          int phys = (colc >> 3) ^ (lrow & 7);
          cb[lrow * 128 + phys * 8 + (colc & 7)] = (f16)(acc[mt][nt][r] + bv);
        }
      }
    }
    __syncthreads();
    const int row = tid & 127, h = tid >> 7;   // octet = 8 consecutive rows (R0-style spread)
    f16* gout = (f16*)Cout + (row0 + row) * NCOLS + col0 + h * 64;
    const f16* src = cb + row * 128;
#pragma unroll
    for (int j = 0; j < 8; ++j) {
      f16x8 v = *(const f16x8*)(src + (((h * 8 + j) ^ (row & 7)) * 8));
      *(f16x8*)(gout + j * 8) = v;
    }
  } else {
    // ---- R0 scalar f32 epilogue (measured fine: 951 TF) ----
#pragma unroll
    for (int mt = 0; mt < 4; ++mt) {
#pragma unroll
      for (int nt = 0; nt < 4; ++nt) {
        long c = col0 + wc + nt * 16 + rl;
        float bv = bias[c];
#pragma unroll
        for (int r = 0; r < 4; ++r) {
          long rr = row0 + wr + mt * 16 + g * 4 + r;
          ((float*)Cout)[rr * NCOLS + c] = acc[mt][nt][r] + bv;
        }
      }
    }
  }
}

// ---------------- V transpose: qkv v-part -> vt[b*16+h][80][2048] ----------------
__global__ void k_vt(const f16* __restrict__ qkv, f16* __restrict__ vt) {
  __shared__ __align__(16) f16 T[128 * 136];
  int bid = blockIdx.x;              // 64 bh * 16 s-chunks
  int sc16 = bid & 15, bh = bid >> 4;
  int b = bh >> 4, h = bh & 15;
  int s0 = sc16 * 128;
  int t = threadIdx.x;
#pragma unroll
  for (int i = 0; i < 5; ++i) {
    int cid = i * 256 + t;           // 1280 = 128 s * 10 chunks
    int s = cid / 10, c = cid % 10;
    const f16* g = qkv + (size_t)((s0 + s) * 4 + b) * 3840 + 2560 + h * 80 + c * 8;
    f16x8 v = *(const f16x8*)g;
    int phys = c ^ ((s >> 3) & 7);
    *(f16x8*)(T + s * 136 + phys * 8) = v;
  }
  __syncthreads();
#pragma unroll
  for (int i = 0; i < 5; ++i) {
    int oid = i * 256 + t;           // 1280 = 80 hd * 16 s-subchunks
    int sc8 = oid & 15, hd = oid >> 4;
    f16x8 o;
#pragma unroll
    for (int j = 0; j < 8; ++j) {
      int row = sc8 * 8 + j;
      int phys = (hd >> 3) ^ (sc8 & 7);
      o[j] = T[row * 136 + phys * 8 + (hd & 7)];
    }
    *(f16x8*)(vt + (size_t)(bh * 80 + hd) * 2048 + s0 + sc8 * 8) = o;
  }
}

// ---------------- windowed attention ----------------
// block: (b, h, seg, qc) ; 512 threads = 8 waves * 16 queries
__global__ __launch_bounds__(512, 2)
void k_attn(const f16* __restrict__ qkv, const f16* __restrict__ vt,
            f16* __restrict__ ctx)
{
  __shared__ __align__(16) f16 sK[256 * 104];   // keys x (80 + zero-pad to 96, stride 104)
  __shared__ __align__(16) f16 sV[80 * 264];    // hd x 256 keys (stride 264)
  __shared__ __align__(16) f16 sP[128 * 72];    // q x 64-key chunk (stride 72)

  const int bid = blockIdx.x;                   // 1024
  const int qc = bid & 1, seg = (bid >> 1) & 7, h = (bid >> 4) & 15, b = bid >> 8;
  const int t = threadIdx.x;
  const int wave = t >> 6, lane = t & 63;
  const int s_key0 = seg * 256;

  // stage K (k-part of qkv, col base 1280 + h*80)
#pragma unroll
  for (int i = 0; i < 5; ++i) {
    int cid = i * 512 + t;                      // 2560 = 256 keys * 10 chunks
    int key = cid / 10, c = cid % 10;
    const f16* g = qkv + (size_t)((s_key0 + key) * 4 + b) * 3840 + 1280 + h * 80 + c * 8;
    *(f16x8*)(sK + key * 104 + c * 8) = *(const f16x8*)g;
  }
  { // zero cols 80..95
    int key = t >> 1, c = t & 1;
    *(f16x8*)(sK + key * 104 + 80 + c * 8) = zero8();
  }
  // stage V from vt
#pragma unroll
  for (int i = 0; i < 5; ++i) {
    int cid = i * 512 + t;                      // 2560 = 80 hd * 32 chunks
    int hd = cid >> 5, c = cid & 31;
    const f16* g = vt + (size_t)((b * 16 + h) * 80 + hd) * 2048 + s_key0 + c * 8;
    *(f16x8*)(sV + hd * 264 + c * 8) = *(const f16x8*)g;
  }

  // Q fragments direct from global (col base h*80); wave owns 16 queries
  const int q0 = s_key0 + qc * 128 + wave * 16;
  const int rl = lane & 15, g = lane >> 4;
  f16x8 qf[3];
  {
    const f16* gq = qkv + (size_t)((q0 + rl) * 4 + b) * 3840 + h * 80;
    qf[0] = *(const f16x8*)(gq + g * 8);
    qf[1] = *(const f16x8*)(gq + 32 + g * 8);
    if (g < 2) qf[2] = *(const f16x8*)(gq + 64 + g * 8);
    else       qf[2] = zero8();
  }
  __syncthreads();

  // QK^T : sc[nt] covers keys nt*16+(lane&15), rows g*4+r
  f32x4 sc[16];
#pragma unroll
  for (int nt = 0; nt < 16; ++nt) sc[nt] = (f32x4){0.f, 0.f, 0.f, 0.f};
#pragma unroll
  for (int nt = 0; nt < 16; ++nt) {
#pragma unroll
    for (int kk = 0; kk < 3; ++kk) {
      f16x8 bf = *(const f16x8*)(sK + (nt * 16 + rl) * 104 + kk * 32 + g * 8);
      sc[nt] = __builtin_amdgcn_mfma_f32_16x16x32_f16(qf[kk], bf, sc[nt], 0, 0, 0);
    }
  }

  // softmax (exact, full 256-key window in regs)
  const float scale = 0.11180339887498949f;
  float inv[4];
#pragma unroll
  for (int r = 0; r < 4; ++r) {
    float m = -1e30f;
#pragma unroll
    for (int nt = 0; nt < 16; ++nt) m = fmaxf(m, sc[nt][r]);
#pragma unroll
    for (int off = 8; off >= 1; off >>= 1) m = fmaxf(m, __shfl_xor(m, off));
    m *= scale;
    float sum = 0.f;
#pragma unroll
    for (int nt = 0; nt < 16; ++nt) {
      float p = __expf(sc[nt][r] * scale - m);
      sc[nt][r] = p;
      sum += p;
    }
#pragma unroll
    for (int off = 8; off >= 1; off >>= 1) sum += __shfl_xor(sum, off);
    inv[r] = 1.0f / sum;
  }

  // PV in 4 chunks of 64 keys; P bounced through WAVE-PRIVATE sP rows.
  // No block barriers: each wave reads only rows it wrote (compiler orders
  // same-wave LDS write->read via lgkmcnt).
  f32x4 o[5];
#pragma unroll
  for (int nt = 0; nt < 5; ++nt) o[nt] = (f32x4){0.f, 0.f, 0.f, 0.f};
  const int prow0 = wave * 16;
  for (int ch = 0; ch < 4; ++ch) {
#pragma unroll
    for (int f = 0; f < 4; ++f) {
      int nt = ch * 4 + f;
#pragma unroll
      for (int r = 0; r < 4; ++r)
        sP[(prow0 + g * 4 + r) * 72 + f * 16 + rl] = (f16)sc[nt][r];
    }
#pragma unroll
    for (int kk = 0; kk < 2; ++kk) {
      f16x8 pa = *(const f16x8*)(sP + (prow0 + rl) * 72 + kk * 32 + g * 8);
#pragma unroll
      for (int nt = 0; nt < 5; ++nt) {
        f16x8 vb = *(const f16x8*)(sV + (nt * 16 + rl) * 264 + ch * 64 + kk * 32 + g * 8);
        o[nt] = __builtin_amdgcn_mfma_f32_16x16x32_f16(pa, vb, o[nt], 0, 0, 0);
      }
    }
  }

  // epilogue: normalize, store ctx fp16
#pragma unroll
  for (int nt = 0; nt < 5; ++nt) {
    int hd = nt * 16 + rl;
#pragma unroll
    for (int r = 0; r < 4; ++r) {
      long qrow = q0 + g * 4 + r;
      float v = o[nt][r] * inv[r];
      ctx[(qrow * 4 + b) * 1280 + h * 80 + hd] = (f16)v;
    }
  }
}

extern "C" void kernel_launch(void* const* d_in, const int* in_sizes, int n_in,
                              void* d_out, int out_size, void* d_ws, size_t ws_size,
                              hipStream_t stream)
{
  const float* x     = (const float*)d_in[0];
  const float* Wqkv  = (const float*)d_in[1];
  const float* bqkv  = (const float*)d_in[2];
  const float* Wproj = (const float*)d_in[3];
  const float* bproj = (const float*)d_in[4];

  char* ws = (char*)d_ws;
  f16* X16   = (f16*)(ws);                 // 20,971,520 B (reused as CTX16 after gemm1)
  f16* WQT   = (f16*)(ws + 20971520);      //  9,830,400 B
  f16* WPT   = (f16*)(ws + 30801920);      // 13,107,200 B
  f16* QKV16 = (f16*)(ws + 43909120);      // 62,914,560 B
  f16* VT    = (f16*)(ws + 106823680);     // 20,971,520 B  (total 127,795,200 B)
  f16* CTX16 = X16;                        // x dead after gemm1

  k_cvt_x<<<4096, 256, 0, stream>>>(x, X16, 8192 * 1280 / 4);
  k_cvt_w_t<<<40 * 120, 256, 0, stream>>>(Wqkv, WQT, 3840);
  k_cvt_w_t<<<40 * 160, 256, 0, stream>>>(Wproj, WPT, 5120);
  gemm_nt<3840, true ><<<64 * 30, 256, 0, stream>>>(X16, WQT, bqkv, QKV16);
  k_vt<<<1024, 256, 0, stream>>>(QKV16, VT);
  k_attn<<<1024, 512, 0, stream>>>(QKV16, VT, CTX16);
  gemm_nt<5120, false><<<64 * 40, 256, 0, stream>>>(CTX16, WPT, bproj, d_out);
}